// Round 7
// baseline (98.534 us; speedup 1.0000x reference)
//
#include <hip/hip_runtime.h>
#include <math.h>

#define NB 8
#define NH 3
#define NBH 24
#define NP 4096
#define BLK 256
#define RPB 128            // rows per block (4 waves x 32)
#define ROWBLKS (NP / RPB) // 32

typedef _Float16 half4 __attribute__((ext_vector_type(4)));
typedef _Float16 half8 __attribute__((ext_vector_type(8)));
typedef float floatx16 __attribute__((ext_vector_type(16)));

// Forced v_min3_f32: fuses the 3-input min AND forces MFMA results into VGPRs
// (the "v" constraints make AGPR parking cost a copy, so the RA avoids it).
#define MIN3(r, a, b) asm("v_min3_f32 %0, %0, %1, %2" : "+v"(r) : "v"(a), "v"(b))

// out[0] = 25 * sum_b || N_b N_b^T - I ||_F  (plain store; runs before chamfer adds)
__global__ void reg_kernel(const float* __restrict__ planes, float* __restrict__ out) {
    const int l = threadIdx.x;
    float r = 0.0f;
    if (l < NB) {
        float n[NH][3];
        for (int hh = 0; hh < NH; ++hh) {
            const float* pl = planes + (l * NH + hh) * 4;
            float a0 = pl[0], a1 = pl[1], a2 = pl[2];
            float inv = 1.0f / sqrtf(a0 * a0 + a1 * a1 + a2 * a2);
            n[hh][0] = a0 * inv; n[hh][1] = a1 * inv; n[hh][2] = a2 * inv;
        }
        float fro = 0.0f;
        for (int i = 0; i < NH; ++i)
            for (int j = 0; j < NH; ++j) {
                float d = n[i][0] * n[j][0] + n[i][1] * n[j][1] + n[i][2] * n[j][2]
                          - (i == j ? 1.0f : 0.0f);
                fro += d * d;
            }
        r = 25.0f * sqrtf(fro);
    }
    for (int o = 32; o; o >>= 1) r += __shfl_down(r, o);
    if (l == 0) out[0] = r;
}

// D = A(32x16)*B(16x32) + C,  K=4 real: A row = [r0,r1,r2,1,0...]; B col =
// [-2c0,-2c1,-2c2,csq, zeros]; C = rsq(row) -> D = full squared distance.
// Block loops over dir (re-staging cols) so grid = 768 = exactly 3 blocks/CU
// (no tail pass). __launch_bounds__(256,3) -> 170-reg budget: with manual
// 1-deep pipelining (no unroll) only 2 MFMA results live -> all-VGPR, no
// accvgpr traffic. min over cols via v_min3; clamp after min (exact).
__global__ void __launch_bounds__(BLK, 3) chamfer_mfma(const float* __restrict__ pts,
                                                       const float* __restrict__ planes,
                                                       float* __restrict__ out) {
    __shared__ _Float16 qcols[NP * 4];   // 32 KB: per col [-2c0,-2c1,-2c2,csq]
    __shared__ float rsqbuf[RPB];
    __shared__ float bsum[4];

    const int tid  = threadIdx.x;
    const int lane = tid & 63;
    const int wave = tid >> 6;
    const int bh   = blockIdx.y;
    const int b    = bh / NH;

    const float* pl = planes + bh * 4;
    float n0 = pl[0], n1 = pl[1], n2 = pl[2], off = pl[3];
    float inv = 1.0f / sqrtf(n0 * n0 + n1 * n1 + n2 * n2);
    n0 *= inv; n1 *= inv; n2 *= inv;

    const float* bp = pts + (size_t)b * NP * 3;
    const half4 z4 = {(_Float16)0.0f, (_Float16)0.0f, (_Float16)0.0f, (_Float16)0.0f};
    const int h = lane >> 5;

    float total = 0.0f;

    for (int dir = 0; dir < 2; ++dir) {
        // stage 4096 cols (reflected when dir==0)
        for (int i = tid; i < NP; i += BLK) {
            float y0 = bp[i * 3 + 0], y1 = bp[i * 3 + 1], y2 = bp[i * 3 + 2];
            if (!dir) { float t = 2.0f * (n0 * y0 + n1 * y1 + n2 * y2 + off); y0 -= t * n0; y1 -= t * n1; y2 -= t * n2; }
            float csq = y0 * y0 + y1 * y1 + y2 * y2;
            half4 v = { (_Float16)(-2.0f * y0), (_Float16)(-2.0f * y1),
                        (_Float16)(-2.0f * y2), (_Float16)csq };
            *(half4*)&qcols[i * 4] = v;
        }

        // A fragment: lane m = lane&31, k = (lane>>5)*8 + j; only lanes<32, k<4 real
        const int rlocal = wave * 32 + (lane & 31);
        const int row = blockIdx.x * RPB + rlocal;
        half8 afrag = {0, 0, 0, 0, 0, 0, 0, 0};
        {
            float a0 = bp[row * 3 + 0], a1 = bp[row * 3 + 1], a2 = bp[row * 3 + 2];
            if (dir) { float t = 2.0f * (n0 * a0 + n1 * a1 + n2 * a2 + off); a0 -= t * n0; a1 -= t * n1; a2 -= t * n2; }
            if (lane < 32) {
                rsqbuf[rlocal] = a0 * a0 + a1 * a1 + a2 * a2;
                afrag[0] = (_Float16)a0; afrag[1] = (_Float16)a1;
                afrag[2] = (_Float16)a2; afrag[3] = (_Float16)1.0f;
            }
        }
        __syncthreads();

        // C fragment: rsq per output row (C/D: col=lane&31, row=(j&3)+8*(j>>2)+4*(lane>>5))
        floatx16 crsq;
        #pragma unroll
        for (int j = 0; j < 16; ++j)
            crsq[j] = rsqbuf[wave * 32 + (j & 3) + 8 * (j >> 2) + 4 * h];

        float rm[16];
        #pragma unroll
        for (int j = 0; j < 16; ++j) rm[j] = 1e30f;

        // B frag: lane covers cols ≡ (lane&31) mod 32; lanes 32-63 duplicate
        // (broadcast); k>=4 half zeros (multiplies A-zeros).
        const _Float16* bcol = &qcols[(lane & 31) * 4];

        half4 c0 = *(const half4*)(bcol);
        half4 c1 = *(const half4*)(bcol + 128);
        #pragma unroll 1
        for (int t = 0; t < 126; t += 2) {
            half8 B0 = __builtin_shufflevector(c0, z4, 0, 1, 2, 3, 4, 5, 6, 7);
            half8 B1 = __builtin_shufflevector(c1, z4, 0, 1, 2, 3, 4, 5, 6, 7);
            floatx16 d0 = __builtin_amdgcn_mfma_f32_32x32x16_f16(afrag, B0, crsq, 0, 0, 0);
            floatx16 d1 = __builtin_amdgcn_mfma_f32_32x32x16_f16(afrag, B1, crsq, 0, 0, 0);
            c0 = *(const half4*)(bcol + (t + 2) * 128);   // prefetch next pair
            c1 = *(const half4*)(bcol + (t + 3) * 128);   // (hides MFMA latency)
            #pragma unroll
            for (int j = 0; j < 16; ++j)
                MIN3(rm[j], d0[j], d1[j]);
        }
        {   // peeled last iteration (no prefetch past end of qcols)
            half8 B0 = __builtin_shufflevector(c0, z4, 0, 1, 2, 3, 4, 5, 6, 7);
            half8 B1 = __builtin_shufflevector(c1, z4, 0, 1, 2, 3, 4, 5, 6, 7);
            floatx16 d0 = __builtin_amdgcn_mfma_f32_32x32x16_f16(afrag, B0, crsq, 0, 0, 0);
            floatx16 d1 = __builtin_amdgcn_mfma_f32_32x32x16_f16(afrag, B1, crsq, 0, 0, 0);
            #pragma unroll
            for (int j = 0; j < 16; ++j)
                MIN3(rm[j], d0[j], d1[j]);
        }

        // min across the 32 lanes sharing each row, then clamp + sum
        #pragma unroll
        for (int j = 0; j < 16; ++j) {
            float v = rm[j];
            v = fminf(v, __shfl_xor(v, 1));
            v = fminf(v, __shfl_xor(v, 2));
            v = fminf(v, __shfl_xor(v, 4));
            v = fminf(v, __shfl_xor(v, 8));
            v = fminf(v, __shfl_xor(v, 16));
            rm[j] = v;
        }
        float s = 0.0f;
        #pragma unroll
        for (int j = 0; j < 16; ++j) s += fmaxf(rm[j], 0.0f);  // clamp after min
        s += __shfl_xor(s, 32);   // combine the two 16-row halves of the wave
        total += s;

        __syncthreads();   // qcols/rsqbuf safe to overwrite for next dir
    }

    if (lane == 0) bsum[wave] = total;
    __syncthreads();
    if (tid == 0)
        atomicAdd(out, (bsum[0] + bsum[1] + bsum[2] + bsum[3]) * (1.0f / (float)(NB * NP)));
}

extern "C" void kernel_launch(void* const* d_in, const int* in_sizes, int n_in,
                              void* d_out, int out_size, void* d_ws, size_t ws_size,
                              hipStream_t stream) {
    const float* planes = (const float*)d_in[0];  // (8,3,4) fp32
    const float* pts    = (const float*)d_in[1];  // (8,4096,3) fp32
    float* out          = (float*)d_out;

    reg_kernel<<<1, 64, 0, stream>>>(planes, out);   // initializes out[0]

    dim3 grid(ROWBLKS, NBH);
    chamfer_mfma<<<grid, BLK, 0, stream>>>(pts, planes, out);
}